// Round 10
// baseline (457.326 us; speedup 1.0000x reference)
//
#include <hip/hip_runtime.h>
#include <hip/hip_bf16.h>
#include <math.h>

// VSN: B=32,T=512,V=16,D=128. prep (weights->bf16), varA (per-var GRN,
// h-in-registers, fragment-native stacked layout, 69KB LDS -> 2 blocks/CU),
// softB (64-row blocks, linear-copy staging). Fallback: fused kernel.
#define NVAR 16
#define ND 128
#define NVD 2048
#define NROWS 16384
#define RTA 256          // rows per varA block
#define NRB 64           // rows per softB block

typedef short s16x8 __attribute__((ext_vector_type(8)));
typedef short s16x4 __attribute__((ext_vector_type(4)));
typedef float f32x4 __attribute__((ext_vector_type(4)));
typedef unsigned short u16;

#define MFMA(a,b,c) __builtin_amdgcn_mfma_f32_16x16x32_bf16((a),(b),(c),0,0,0)

// ws layout (u16 units)
#define OFF_W2  0
#define OFF_WG  262144
#define OFF_SW1 524288
#define OFF_SWS 786432
#define OFF_SW2 819200
#define OFF_SWG 821248
#define WS_ELEMS 823296
#define OFF_STK 823296
#define STK_ELEMS ((size_t)NROWS*NVD)
#define WS_NEEDED_BYTES (((size_t)WS_ELEMS + STK_ELEMS)*2)
// stacked fragment-native layout: stk[v][rowgrp][ctp 4][n 16][32 elems]
//   element (v,row,o): grp=row>>4, n=row&15, ctp=o>>5, e=hr_e*8+(half<<2)|j
//   with o = ctp*32 + half*16 + hr_e*4 + j
#define SV_ELEMS ((size_t)(NROWS/16)*2048)

// manual RNE f32->bf16 (pure ALU; __float2bfloat16 + addr-cast allocas -> spill, R8)
__device__ __forceinline__ unsigned f2bf(float f){
    union { float f; unsigned u; } c; c.f = f;
    unsigned u = c.u;
    u += 0x7fffu + ((u >> 16) & 1u);
    return u >> 16;
}
__device__ __forceinline__ float bf2f(unsigned bits){
    union { unsigned u; float f; } c; c.u = bits << 16;
    return c.f;
}
// fast ELU / sigmoid: single v_exp_f32 each
__device__ __forceinline__ float eluf(float x){ return x > 0.f ? x : __expf(x) - 1.f; }
__device__ __forceinline__ float sigm(float x){
    return __builtin_amdgcn_rcpf(1.f + __expf(-x));
}

__device__ __forceinline__ int offHs(int r, int c){
    return r*128 + ((((c>>3) ^ (r&7))<<3) | (c&7));
}
__device__ __forceinline__ int offBig(int r, int c){
    return r*2048 + ((((c>>3) ^ (r&7))<<3) | (c&7));
}

__global__ void prep_kernel(const float* __restrict__ W2, const float* __restrict__ Wg,
                            const float* __restrict__ sW1, const float* __restrict__ sWs,
                            const float* __restrict__ sW2, const float* __restrict__ sWg,
                            u16* __restrict__ ws){
    int i = blockIdx.x*256 + threadIdx.x;
    if (i >= WS_ELEMS) return;
    float v;
    if      (i < OFF_WG)  v = W2[i];
    else if (i < OFF_SW1) v = Wg[i-OFF_WG];
    else if (i < OFF_SWS) v = sW1[i-OFF_SW1];
    else if (i < OFF_SW2) v = sWs[i-OFF_SWS];
    else if (i < OFF_SWG) v = sW2[i-OFF_SW2];
    else                  v = sWg[i-OFF_SWG];
    ws[i] = (u16)f2bf(v);
}

// ---------------- Kernel A: per-var GRN -> stacked bf16 ----------------
// grid (NROWS/256, NVAR), 512 threads. Weights LDS-resident (69KB total ->
// 2 blocks/CU). h computed directly into MFMA B-fragments (no LDS);
// output stored in fragment-native layout (1KB contiguous per instr).
__global__ __launch_bounds__(512, 2)
void vsn_varA(const float* __restrict__ x,
              const float* __restrict__ W1, const float* __restrict__ b1,
              const float* __restrict__ b2, const float* __restrict__ bg,
              const float* __restrict__ Wsk, const float* __restrict__ bsk,
              const float* __restrict__ gamma, const float* __restrict__ beta,
              u16* __restrict__ ws)
{
    __shared__ u16 lw2[128*128];     // 32KB, swizzled
    __shared__ u16 lwg[128*128];     // 32KB, swizzled
    __shared__ float lp[8*128];      // W1,b1,b2,bg,Ws,bs,gamma,beta (4KB)
    __shared__ float lxv[RTA];       // x[:, v] (1KB)

    const int t = threadIdx.x, w = t>>6, l = t&63;
    const int hr = l>>4, c16 = l&15;
    const int v = blockIdx.y;
    const int row0 = blockIdx.x*RTA;

    // stage weights (w2 iters 0-3, wg iters 4-7)
    #pragma unroll
    for (int i=0;i<8;++i){
        int cid = i*512 + t;              // 16B chunk id, 0..4095
        int mat = cid>>11, within = cid&2047;
        int r = within>>4, c8 = within&15;
        const u16* src = ws + (mat? OFF_WG:OFF_W2) + v*16384 + r*128 + c8*8;
        s16x8 val = *reinterpret_cast<const s16x8*>(src);
        u16* dst = (mat? lwg:lw2) + r*128 + ((c8 ^ (r&7))<<3);
        *reinterpret_cast<s16x8*>(dst) = val;
    }
    if (t < 128){
        lp[t]     = W1[v*ND+t];    lp[128+t] = b1[v*ND+t];
        lp[256+t] = b2[v*ND+t];    lp[384+t] = bg[v*ND+t];
        lp[512+t] = Wsk[v*ND+t];   lp[640+t] = bsk[v*ND+t];
        lp[768+t] = gamma[v*ND+t]; lp[896+t] = beta[v*ND+t];
    }
    if (t < RTA) lxv[t] = x[(size_t)(row0+t)*NVAR + v];
    __syncthreads();

    #pragma unroll 1
    for (int pass=0; pass<2; ++pass){
        const int lrow0 = (w + pass*8)*16;
        const float xv = lxv[lrow0 + c16];   // this lane's row (n=c16)

        // h B-fragments computed directly in registers:
        // lane (c16,hr) holds h[row=c16][k = ks*32 + hr*8 + j]
        s16x8 B[4];
        #pragma unroll
        for (int ks=0;ks<4;++ks){
            s16x8 o;
            #pragma unroll
            for (int j=0;j<8;++j){
                int c = ks*32 + hr*8 + j;
                o[j] = (short)f2bf(eluf(xv*lp[c] + lp[128+c]));
            }
            B[ks] = o;
        }

        float y[8][4];
        #pragma unroll
        for (int ct=0; ct<8; ++ct){
            f32x4 a2 = {0.f,0.f,0.f,0.f}, ag = {0.f,0.f,0.f,0.f};
            const int wr = ct*16 + c16;
            #pragma unroll
            for (int ks=0;ks<4;++ks){
                int chunk = (ks*4 + hr) ^ (wr&7);
                s16x8 A2 = *reinterpret_cast<const s16x8*>(lw2 + wr*128 + chunk*8);
                a2 = MFMA(A2, B[ks], a2);
            }
            #pragma unroll
            for (int ks=0;ks<4;++ks){
                int chunk = (ks*4 + hr) ^ (wr&7);
                s16x8 Ag = *reinterpret_cast<const s16x8*>(lwg + wr*128 + chunk*8);
                ag = MFMA(Ag, B[ks], ag);
            }
            const int obb = ct*16 + hr*4;
            float4 b2v = *reinterpret_cast<const float4*>(&lp[256+obb]);
            float4 bgv = *reinterpret_cast<const float4*>(&lp[384+obb]);
            float4 wsv = *reinterpret_cast<const float4*>(&lp[512+obb]);
            float4 bsv = *reinterpret_cast<const float4*>(&lp[640+obb]);
            #pragma unroll
            for (int j=0;j<4;++j){
                float h2 = a2[j] + reinterpret_cast<const float*>(&b2v)[j];
                float gg = sigm(ag[j] + reinterpret_cast<const float*>(&bgv)[j]);
                float sk = xv*reinterpret_cast<const float*>(&wsv)[j]
                           + reinterpret_cast<const float*>(&bsv)[j];
                y[ct][j] = gg*h2 + (1.f-gg)*sk;
            }
        }
        // wave-local LN over 128 dims of row n=c16
        float s = 0.f, q = 0.f;
        #pragma unroll
        for (int ct=0;ct<8;++ct)
            #pragma unroll
            for (int j=0;j<4;++j){ float yy = y[ct][j]; s += yy; q += yy*yy; }
        s += __shfl_xor(s, 16); s += __shfl_xor(s, 32);
        q += __shfl_xor(q, 16); q += __shfl_xor(q, 32);
        float mean = s*(1.f/ND);
        float inv  = rsqrtf(q*(1.f/ND) - mean*mean + 1e-5f);

        // normalize + pack + store fragment-native: per ctp, wave writes
        // 1KB contiguous (lane 16B at c16*32 + hr*8 elems)
        const int grp = blockIdx.x*16 + w + pass*8;
        u16* stkb = ws + OFF_STK + (size_t)v*SV_ELEMS + (size_t)grp*2048;
        #pragma unroll
        for (int ctp=0; ctp<4; ++ctp){
            s16x8 o;
            #pragma unroll
            for (int hh=0; hh<2; ++hh){
                int ct = ctp*2 + hh;
                const int obb = ct*16 + hr*4;
                float4 gm = *reinterpret_cast<const float4*>(&lp[768+obb]);
                float4 bt = *reinterpret_cast<const float4*>(&lp[896+obb]);
                #pragma unroll
                for (int j=0;j<4;++j){
                    float z = (y[ct][j]-mean)*inv*reinterpret_cast<const float*>(&gm)[j]
                              + reinterpret_cast<const float*>(&bt)[j];
                    o[hh*4+j] = (short)f2bf(z);
                }
            }
            *reinterpret_cast<s16x8*>(stkb + ctp*512 + c16*32 + hr*8) = o;
        }
        // no barrier: LDS is read-only in this loop
    }
}

// ---------------- Kernel B: softmax GRN + weighted sum (64 rows/blk) ----
// abuf layout: [vrel2][rg4][ctp4][n16][32], 16B-units swizzled u^=(n>>1)&3
__device__ __forceinline__ s16x8 ldA(const u16* abuf, int vrel, int rg, int ctp, int n, int hr){
    int base = (((vrel*4 + rg)*4 + ctp)*16 + n)*32;
    int fn = (n>>1)&3;
    int u0 = (hr&1)*2;
    int half = (hr>>1)*4;
    s16x4 lo = *reinterpret_cast<const s16x4*>(abuf + base + (((u0  )^fn)<<3) + half);
    s16x4 hi = *reinterpret_cast<const s16x4*>(abuf + base + (((u0+1)^fn)<<3) + half);
    s16x8 r;
    r[0]=lo[0]; r[1]=lo[1]; r[2]=lo[2]; r[3]=lo[3];
    r[4]=hi[0]; r[5]=hi[1]; r[6]=hi[2]; r[7]=hi[3];
    return r;
}

__global__ __launch_bounds__(512, 4)
void vsn_softB(const u16* __restrict__ ws,
               const float* __restrict__ sb1, const float* __restrict__ sb2,
               const float* __restrict__ sbg, const float* __restrict__ sbs,
               const float* __restrict__ sgamma, const float* __restrict__ sbeta,
               float* __restrict__ out_proc, float* __restrict__ out_w)
{
    __shared__ u16   abuf[16384];    // 32KB K-chunk (2 vars x 4 rowgrps)
    __shared__ u16   hsb[64*128];    // 16KB hs bf16, swizzled
    __shared__ float pps_[2*64*16];  // sks partials (2 k-halves)
    __shared__ float pph[64*16];
    __shared__ float ppg[64*16];
    __shared__ float sksf[64*16];
    __shared__ float wgtb[64*16];

    float* pps = pps_;

    const int t = threadIdx.x, w = t>>6, l = t&63;
    const int hr = l>>4, c16 = l&15;
    const int row0 = blockIdx.x * NRB;
    const int grp0 = row0 >> 4;
    const int orow = w*16 + c16;
    const int rgs = w & 3;        // sks row-group
    const int khf = w >> 2;       // sks k-half

    const u16* stk  = ws + OFF_STK;
    const u16* sW1b = ws + OFF_SW1;
    const u16* sWsb = ws + OFF_SWS;

    f32x4 accHs[4] = {{0,0,0,0},{0,0,0,0},{0,0,0,0},{0,0,0,0}};
    f32x4 accSk = {0,0,0,0};

    #pragma unroll 1
    for (int kt=0; kt<8; ++kt){
        // stage: linear copy of 2 vars x 4 rowgrps (16B units), swizzled dst
        #pragma unroll
        for (int i=0;i<4;++i){
            int cid = i*512 + t;          // [vrel1][rg2][ctp2][n4][u2] bits
            int vv  = kt*2 + (cid>>10);
            int rg  = (cid>>8)&3;
            int n   = (cid>>2)&15;
            int u   = cid&3;
            const u16* src = stk + (size_t)vv*SV_ELEMS + (size_t)(grp0+rg)*2048
                           + ((cid>>2)&63)*32 + u*8;
            s16x8 val = *reinterpret_cast<const s16x8*>(src);
            *reinterpret_cast<s16x8*>(abuf + (cid>>2)*32 + ((u ^ ((n>>1)&3))<<3)) = val;
        }
        __syncthreads();
        // hs GEMM: B-frag loaded once per ks, reused for 4 row-groups
        #pragma unroll
        for (int ks=0; ks<8; ++ks){
            s16x8 bf = *reinterpret_cast<const s16x8*>(
                sW1b + (size_t)orow*NVD + kt*256 + ks*32 + hr*8);
            #pragma unroll
            for (int rg=0; rg<4; ++rg){
                s16x8 af = ldA(abuf, ks>>2, rg, ks&3, c16, hr);
                accHs[rg] = MFMA(af, bf, accHs[rg]);
            }
        }
        // sks: wave covers (row-group rgs, k-half khf)
        #pragma unroll
        for (int kk=0; kk<4; ++kk){
            int ks = khf*4 + kk;
            s16x8 bf = *reinterpret_cast<const s16x8*>(
                sWsb + (size_t)c16*NVD + kt*256 + ks*32 + hr*8);
            s16x8 af = ldA(abuf, ks>>2, rgs, ks&3, c16, hr);
            accSk = MFMA(af, bf, accSk);
        }
        __syncthreads();
    }

    // epilogue: hs -> LDS ; sks partials
    {
        float bb = sb1[orow];
        #pragma unroll
        for (int rg=0; rg<4; ++rg){
            #pragma unroll
            for (int j=0;j<4;++j){
                int r = rg*16 + hr*4 + j;
                hsb[offHs(r, orow)] = (u16)f2bf(eluf(accHs[rg][j] + bb));
            }
        }
        #pragma unroll
        for (int j=0;j<4;++j)
            pps[khf*1024 + (rgs*16 + hr*4 + j)*16 + c16] = accSk[j];
    }
    __syncthreads();

    // sks reduce (+sbs)
    #pragma unroll
    for (int i=0;i<2;++i){
        int idx = i*512 + t;          // r*16+vv
        sksf[idx] = pps[idx] + pps[1024+idx] + sbs[idx&15];
    }
    // h2s/gs: waves 0-3 -> sW2 (rg=w), waves 4-7 -> sWg; full K in-reg
    {
        const u16* Bsrc = (w < 4) ? (ws + OFF_SW2) : (ws + OFF_SWG);
        int rg = w & 3;
        f32x4 acc = {0,0,0,0};
        #pragma unroll
        for (int ks=0; ks<4; ++ks){
            int rr = rg*16 + c16;
            int chunk = (ks*4 + hr) ^ (rr&7);
            s16x8 af = *reinterpret_cast<const s16x8*>(hsb + rr*128 + chunk*8);
            s16x8 bf = *reinterpret_cast<const s16x8*>(Bsrc + c16*ND + ks*32 + hr*8);
            acc = MFMA(af, bf, acc);
        }
        float* dst = (w < 4) ? pph : ppg;
        #pragma unroll
        for (int j=0;j<4;++j)
            dst[(rg*16 + hr*4 + j)*16 + c16] = acc[j];
    }
    __syncthreads();

    // gate-mix, LN over V, softmax -> weights (16 lanes per row)
    #pragma unroll
    for (int it=0; it<2; ++it){
        int r = it*32 + (t>>4), vv = t & 15;
        float h2s = pph[r*16+vv] + sb2[vv];
        float gs  = sigm(ppg[r*16+vv] + sbg[vv]);
        float yv  = gs*h2s + (1.f-gs)*sksf[r*16+vv];
        float ssum = yv, qsum = yv*yv;
        #pragma unroll
        for (int m=1;m<16;m<<=1){ ssum += __shfl_xor(ssum,m,16); qsum += __shfl_xor(qsum,m,16); }
        float mean = ssum*(1.f/NVAR);
        float var  = qsum*(1.f/NVAR) - mean*mean;
        float z = (yv-mean)*rsqrtf(var+1e-5f)*sgamma[vv] + sbeta[vv];
        float mx = z;
        #pragma unroll
        for (int m=1;m<16;m<<=1) mx = fmaxf(mx, __shfl_xor(mx,m,16));
        float e = __expf(z-mx);
        float es = e;
        #pragma unroll
        for (int m=1;m<16;m<<=1) es += __shfl_xor(es,m,16);
        float wgt = e * __builtin_amdgcn_rcpf(es);
        wgtb[r*16+vv] = wgt;
        out_w[(size_t)(row0+r)*NVAR + vv] = wgt;
    }
    __syncthreads();

    // processed = sum_v stacked * weights (fragment-native layout)
    #pragma unroll
    for (int it=0; it<2; ++it){
        int idx = it*512 + t;          // 0..1023
        int r = idx>>4, cu = idx&15;
        int ctp = cu>>2, u = cu&3;
        int grp = (row0+r)>>4, n = r&15;
        float acc[8] = {0,0,0,0,0,0,0,0};
        #pragma unroll
        for (int v=0; v<NVAR; ++v){
            float wv = wgtb[r*16 + v];
            const u16* sp = stk + (size_t)v*SV_ELEMS + (size_t)grp*2048
                          + (ctp*16+n)*32 + u*8;
            s16x8 sv = *reinterpret_cast<const s16x8*>(sp);
            #pragma unroll
            for (int k=0;k<8;++k) acc[k] += bf2f((u16)sv[k]) * wv;
        }
        // element k -> o = ctp*32 + (k>>2)*16 + u*4 + (k&3)
        float* op = out_proc + (size_t)(row0+r)*ND + ctp*32 + u*4;
        float4 lo = { acc[0], acc[1], acc[2], acc[3] };
        float4 hi = { acc[4], acc[5], acc[6], acc[7] };
        *reinterpret_cast<float4*>(op)      = lo;
        *reinterpret_cast<float4*>(op + 16) = hi;
    }
}

// ---------------- Fallback: fused kernel (verified R3 lineage) ----------
__global__ __launch_bounds__(512, 4)
void vsn_fused(const float* __restrict__ x,
               const float* __restrict__ W1, const float* __restrict__ b1,
               const float* __restrict__ b2, const float* __restrict__ bg,
               const float* __restrict__ Wsk, const float* __restrict__ bsk,
               const float* __restrict__ gamma, const float* __restrict__ beta,
               const float* __restrict__ sb1, const float* __restrict__ sb2,
               const float* __restrict__ sbg, const float* __restrict__ sbs,
               const float* __restrict__ sgamma, const float* __restrict__ sbeta,
               const u16* __restrict__ ws,
               float* __restrict__ out_proc, float* __restrict__ out_w)
{
    __shared__ u16   big[16*2048];
    __shared__ u16   hsb[16*128];
    __shared__ float pp[8*256];
    __shared__ float psumbuf[256];
    __shared__ float sksbuf[256];
    __shared__ float sx[256];

    float* psum  = psumbuf;
    float* psum2 = psumbuf + 128;

    const int t   = threadIdx.x;
    const int w   = t >> 6;
    const int l   = t & 63;
    const int hr  = l >> 4;
    const int c16 = l & 15;
    const int row0 = blockIdx.x * 16;
    const int orow = w*16 + c16;

    if (t < 256) sx[t] = x[row0*NVAR + t];
    __syncthreads();

    const u16* W2b = ws + OFF_W2;
    const u16* Wgb = ws + OFF_WG;

    for (int v = 0; v < NVAR; ++v){
        #pragma unroll
        for (int i = 0; i < 4; ++i){
            int idx = i*512 + t;
            int r = idx >> 7, d = idx & 127;
            float hv = eluf(sx[r*NVAR+v]*W1[v*ND+d] + b1[v*ND+d]);
            big[offBig(r, v*ND+d)] = (u16)f2bf(hv);
        }
        __syncthreads();

        s16x8 A[4];
        #pragma unroll
        for (int ks = 0; ks < 4; ++ks)
            A[ks] = *reinterpret_cast<const s16x8*>(&big[offBig(c16, v*ND + ks*32 + hr*8)]);
        const s16x8* B2p = reinterpret_cast<const s16x8*>(W2b + v*ND*ND + orow*ND + hr*8);
        const s16x8* Bgp = reinterpret_cast<const s16x8*>(Wgb + v*ND*ND + orow*ND + hr*8);
        f32x4 acc2 = {0.f,0.f,0.f,0.f}, accg = {0.f,0.f,0.f,0.f};
        #pragma unroll
        for (int ks = 0; ks < 4; ++ks) acc2 = MFMA(A[ks], B2p[ks*4], acc2);
        #pragma unroll
        for (int ks = 0; ks < 4; ++ks) accg = MFMA(A[ks], Bgp[ks*4], accg);

        const float b2v = b2[v*ND+orow], bgv = bg[v*ND+orow];
        const float wsv = Wsk[v*ND+orow], bsv = bsk[v*ND+orow];
        float y[4];
        #pragma unroll
        for (int j = 0; j < 4; ++j){
            int r = hr*4 + j;
            float h2 = acc2[j] + b2v;
            float g  = sigm(accg[j] + bgv);
            float sk = sx[r*NVAR+v]*wsv + bsv;
            y[j] = g*h2 + (1.f-g)*sk;
        }
        float s[4], q[4];
        #pragma unroll
        for (int j=0;j<4;++j){ s[j]=y[j]; q[j]=y[j]*y[j]; }
        #pragma unroll
        for (int m=1; m<16; m<<=1){
            #pragma unroll
            for (int j=0;j<4;++j){
                s[j] += __shfl_xor(s[j], m, 16);
                q[j] += __shfl_xor(q[j], m, 16);
            }
        }
        if (c16 == 0){
            #pragma unroll
            for (int j=0;j<4;++j){
                psum [(hr*4+j)*8 + w] = s[j];
                psum2[(hr*4+j)*8 + w] = q[j];
            }
        }
        __syncthreads();

        if (t < 16){
            float ss=0.f, qq=0.f;
            #pragma unroll
            for (int ww=0; ww<8; ++ww){ ss += psum[t*8+ww]; qq += psum2[t*8+ww]; }
            float mean = ss*(1.f/ND);
            float var  = qq*(1.f/ND) - mean*mean;
            sksbuf[t]      = mean;
            sksbuf[16 + t] = rsqrtf(var + 1e-5f);
        }
        __syncthreads();

        const float gm = gamma[v*ND+orow], bt = beta[v*ND+orow];
        #pragma unroll
        for (int j=0;j<4;++j){
            int r = hr*4 + j;
            float z = (y[j]-sksbuf[r])*sksbuf[16+r]*gm + bt;
            big[offBig(r, v*ND+orow)] = (u16)f2bf(z);
        }
    }
    __syncthreads();

    const u16* sW1b = ws + OFF_SW1;
    {
        f32x4 acc0 = {0,0,0,0}, acc1 = {0,0,0,0};
        const s16x8* Bp = reinterpret_cast<const s16x8*>(sW1b + orow*NVD + hr*8);
        #pragma unroll 8
        for (int ks = 0; ks < 64; ks += 2){
            s16x8 A0 = *reinterpret_cast<const s16x8*>(&big[offBig(c16, ks*32 + hr*8)]);
            s16x8 A1 = *reinterpret_cast<const s16x8*>(&big[offBig(c16, (ks+1)*32 + hr*8)]);
            acc0 = MFMA(A0, Bp[ks*4],     acc0);
            acc1 = MFMA(A1, Bp[(ks+1)*4], acc1);
        }
        float bb = sb1[orow];
        #pragma unroll
        for (int j=0;j<4;++j){
            int r = hr*4 + j;
            hsb[offHs(r, orow)] = (u16)f2bf(eluf(acc0[j] + acc1[j] + bb));
        }
    }
    const u16* sWsb = ws + OFF_SWS;
    {
        f32x4 acc = {0,0,0,0};
        const s16x8* Bp = reinterpret_cast<const s16x8*>(sWsb + c16*NVD + hr*8);
        #pragma unroll
        for (int kk = 0; kk < 8; ++kk){
            int ks = w*8 + kk;
            s16x8 Af = *reinterpret_cast<const s16x8*>(&big[offBig(c16, ks*32 + hr*8)]);
            acc = MFMA(Af, Bp[ks*4], acc);
        }
        #pragma unroll
        for (int j=0;j<4;++j)
            pp[w*256 + (hr*4+j)*16 + c16] = acc[j];
    }
    __syncthreads();

    if (t < 256){
        float a = sbs[t & 15];
        #pragma unroll
        for (int ww=0; ww<8; ++ww) a += pp[ww*256 + t];
        sksbuf[t] = a;
    }
    __syncthreads();

    {
        const u16* Bsrc = (w < 4) ? (ws + OFF_SW2) : (ws + OFF_SWG);
        const int m = w & 3;
        s16x8 Af = *reinterpret_cast<const s16x8*>(&hsb[offHs(c16, m*32 + hr*8)]);
        s16x8 Bf = *reinterpret_cast<const s16x8*>(Bsrc + c16*ND + m*32 + hr*8);
        f32x4 z4 = {0,0,0,0};
        f32x4 acc = MFMA(Af, Bf, z4);
        #pragma unroll
        for (int j=0;j<4;++j)
            pp[w*256 + (hr*4+j)*16 + c16] = acc[j];
    }
    __syncthreads();

    if (t < 256){
        int r = t >> 4, vv = t & 15;
        float h2s = sb2[vv], gp = sbg[vv];
        #pragma unroll
        for (int j=0;j<4;++j){ h2s += pp[j*256 + t]; gp += pp[(4+j)*256 + t]; }
        float gs = sigm(gp);
        float yv = gs*h2s + (1.f-gs)*sksbuf[t];
        float ssum = yv, qsum = yv*yv;
        #pragma unroll
        for (int m=1;m<16;m<<=1){ ssum += __shfl_xor(ssum,m,16); qsum += __shfl_xor(qsum,m,16); }
        float mean = ssum*(1.f/NVAR);
        float var  = qsum*(1.f/NVAR) - mean*mean;
        float z = (yv-mean)*rsqrtf(var+1e-5f)*sgamma[vv] + sbeta[vv];
        float mx = z;
        #pragma unroll
        for (int m=1;m<16;m<<=1) mx = fmaxf(mx, __shfl_xor(mx,m,16));
        float e = __expf(z-mx);
        float es = e;
        #pragma unroll
        for (int m=1;m<16;m<<=1) es += __shfl_xor(es,m,16);
        float wgt = e/es;
        psumbuf[t] = wgt;
        out_w[(row0+r)*NVAR + vv] = wgt;
    }
    __syncthreads();

    if (t < 256){
        int r = t >> 4, d8 = (t & 15)*8;
        float acc[8] = {0,0,0,0,0,0,0,0};
        #pragma unroll
        for (int v=0; v<NVAR; ++v){
            float wv = psumbuf[r*NVAR + v];
            s16x8 sv = *reinterpret_cast<const s16x8*>(&big[offBig(r, v*ND + d8)]);
            #pragma unroll
            for (int k=0;k<8;++k) acc[k] += bf2f((u16)sv[k]) * wv;
        }
        float* op = &out_proc[(row0+r)*ND + d8];
        #pragma unroll
        for (int k=0;k<8;++k) op[k] = acc[k];
    }
}

extern "C" void kernel_launch(void* const* d_in, const int* in_sizes, int n_in,
                              void* d_out, int out_size, void* d_ws, size_t ws_size,
                              hipStream_t stream) {
    (void)in_sizes; (void)n_in; (void)out_size;
    const float* x     = (const float*)d_in[0];
    const float* W1    = (const float*)d_in[1];
    const float* b1    = (const float*)d_in[2];
    const float* W2    = (const float*)d_in[3];
    const float* b2    = (const float*)d_in[4];
    const float* Wg    = (const float*)d_in[5];
    const float* bg    = (const float*)d_in[6];
    const float* Wsk   = (const float*)d_in[7];
    const float* bsk   = (const float*)d_in[8];
    const float* gamma = (const float*)d_in[9];
    const float* beta  = (const float*)d_in[10];
    const float* sW1   = (const float*)d_in[11];
    const float* sb1   = (const float*)d_in[12];
    const float* sW2   = (const float*)d_in[13];
    const float* sb2   = (const float*)d_in[14];
    const float* sWg   = (const float*)d_in[15];
    const float* sbg   = (const float*)d_in[16];
    const float* sWs   = (const float*)d_in[17];
    const float* sbs   = (const float*)d_in[18];
    const float* sgam  = (const float*)d_in[19];
    const float* sbet  = (const float*)d_in[20];

    u16* ws = (u16*)d_ws;
    float* out_proc = (float*)d_out;
    float* out_w    = out_proc + (size_t)NROWS * ND;

    prep_kernel<<<(WS_ELEMS + 255)/256, 256, 0, stream>>>(W2, Wg, sW1, sWs, sW2, sWg, ws);

    if (ws_size >= WS_NEEDED_BYTES) {
        vsn_varA<<<dim3(NROWS/RTA, NVAR), 512, 0, stream>>>(
            x, W1, b1, b2, bg, Wsk, bsk, gamma, beta, ws);
        vsn_softB<<<NROWS/NRB, 512, 0, stream>>>(
            ws, sb1, sb2, sbg, sbs, sgam, sbet, out_proc, out_w);
    } else {
        vsn_fused<<<NROWS/16, 512, 0, stream>>>(
            x, W1, b1, b2, bg, Wsk, bsk, gamma, beta,
            sb1, sb2, sbg, sbs, sgam, sbet, ws, out_proc, out_w);
    }
}

// Round 11
// 110.482 us; speedup vs baseline: 4.1394x; 4.1394x over previous
//
#include <hip/hip_runtime.h>
#include <hip/hip_bf16.h>
#include <math.h>

// VSN: B=32,T=512,V=16,D=128. prep (weights->bf16), varA (per-var GRN,
// h-in-registers, fragment-native stacked layout, 69KB LDS -> 2 blocks/CU,
// sched_barrier-pinned to avoid VGPR spill), softB (64-row blocks).
#define NVAR 16
#define ND 128
#define NVD 2048
#define NROWS 16384
#define RTA 256          // rows per varA block
#define NRB 64           // rows per softB block

typedef short s16x8 __attribute__((ext_vector_type(8)));
typedef short s16x4 __attribute__((ext_vector_type(4)));
typedef float f32x4 __attribute__((ext_vector_type(4)));
typedef unsigned short u16;

#define MFMA(a,b,c) __builtin_amdgcn_mfma_f32_16x16x32_bf16((a),(b),(c),0,0,0)

// ws layout (u16 units)
#define OFF_W2  0
#define OFF_WG  262144
#define OFF_SW1 524288
#define OFF_SWS 786432
#define OFF_SW2 819200
#define OFF_SWG 821248
#define WS_ELEMS 823296
#define OFF_STK 823296
#define STK_ELEMS ((size_t)NROWS*NVD)
#define WS_NEEDED_BYTES (((size_t)WS_ELEMS + STK_ELEMS)*2)
// stacked fragment-native layout: stk[v][rowgrp][ctp 4][n 16][32 elems]
#define SV_ELEMS ((size_t)(NROWS/16)*2048)

// manual RNE f32->bf16 (pure ALU; __float2bfloat16 + addr-cast allocas -> spill, R8)
__device__ __forceinline__ unsigned f2bf(float f){
    union { float f; unsigned u; } c; c.f = f;
    unsigned u = c.u;
    u += 0x7fffu + ((u >> 16) & 1u);
    return u >> 16;
}
__device__ __forceinline__ float bf2f(unsigned bits){
    union { unsigned u; float f; } c; c.u = bits << 16;
    return c.f;
}
// fast ELU / sigmoid: single v_exp_f32 each
__device__ __forceinline__ float eluf(float x){ return x > 0.f ? x : __expf(x) - 1.f; }
__device__ __forceinline__ float sigm(float x){
    return __builtin_amdgcn_rcpf(1.f + __expf(-x));
}

__device__ __forceinline__ int offHs(int r, int c){
    return r*128 + ((((c>>3) ^ (r&7))<<3) | (c&7));
}
__device__ __forceinline__ int offBig(int r, int c){
    return r*2048 + ((((c>>3) ^ (r&7))<<3) | (c&7));
}

__global__ void prep_kernel(const float* __restrict__ W2, const float* __restrict__ Wg,
                            const float* __restrict__ sW1, const float* __restrict__ sWs,
                            const float* __restrict__ sW2, const float* __restrict__ sWg,
                            u16* __restrict__ ws){
    int i = blockIdx.x*256 + threadIdx.x;
    if (i >= WS_ELEMS) return;
    float v;
    if      (i < OFF_WG)  v = W2[i];
    else if (i < OFF_SW1) v = Wg[i-OFF_WG];
    else if (i < OFF_SWS) v = sW1[i-OFF_SW1];
    else if (i < OFF_SW2) v = sWs[i-OFF_SWS];
    else if (i < OFF_SWG) v = sW2[i-OFF_SW2];
    else                  v = sWg[i-OFF_SWG];
    ws[i] = (u16)f2bf(v);
}

// ---------------- Kernel A: per-var GRN -> stacked bf16 ----------------
// grid (NROWS/256, NVAR), 512 threads. Weights LDS-resident (69KB ->
// 2 blocks/CU). h computed directly into MFMA B-fragments (no LDS).
// sched_barrier(0) pins phase boundaries so peak liveness fits 128 VGPR.
__global__ __launch_bounds__(512, 2)
void vsn_varA(const float* __restrict__ x,
              const float* __restrict__ W1, const float* __restrict__ b1,
              const float* __restrict__ b2, const float* __restrict__ bg,
              const float* __restrict__ Wsk, const float* __restrict__ bsk,
              const float* __restrict__ gamma, const float* __restrict__ beta,
              u16* __restrict__ ws)
{
    __shared__ u16 lw2[128*128];     // 32KB, swizzled
    __shared__ u16 lwg[128*128];     // 32KB, swizzled
    __shared__ float lp[8*128];      // W1,b1,b2,bg,Ws,bs,gamma,beta (4KB)
    __shared__ float lxv[RTA];       // x[:, v] (1KB)

    const int t = threadIdx.x, w = t>>6, l = t&63;
    const int hr = l>>4, c16 = l&15;
    const int v = blockIdx.y;
    const int row0 = blockIdx.x*RTA;

    // stage weights (w2 iters 0-3, wg iters 4-7)
    #pragma unroll
    for (int i=0;i<8;++i){
        int cid = i*512 + t;              // 16B chunk id, 0..4095
        int mat = cid>>11, within = cid&2047;
        int r = within>>4, c8 = within&15;
        const u16* src = ws + (mat? OFF_WG:OFF_W2) + v*16384 + r*128 + c8*8;
        s16x8 val = *reinterpret_cast<const s16x8*>(src);
        u16* dst = (mat? lwg:lw2) + r*128 + ((c8 ^ (r&7))<<3);
        *reinterpret_cast<s16x8*>(dst) = val;
    }
    if (t < 128){
        lp[t]     = W1[v*ND+t];    lp[128+t] = b1[v*ND+t];
        lp[256+t] = b2[v*ND+t];    lp[384+t] = bg[v*ND+t];
        lp[512+t] = Wsk[v*ND+t];   lp[640+t] = bsk[v*ND+t];
        lp[768+t] = gamma[v*ND+t]; lp[896+t] = beta[v*ND+t];
    }
    if (t < RTA) lxv[t] = x[(size_t)(row0+t)*NVAR + v];
    __syncthreads();

    #pragma unroll 1
    for (int pass=0; pass<2; ++pass){
        const int lrow0 = (w + pass*8)*16;
        const float xv = lxv[lrow0 + c16];   // this lane's row (n=c16)

        // h B-fragments computed directly in registers:
        // lane (c16,hr) holds h[row=c16][k = ks*32 + hr*8 + j]
        s16x8 B[4];
        #pragma unroll
        for (int ks=0;ks<4;++ks){
            s16x8 o;
            #pragma unroll
            for (int j=0;j<8;++j){
                int c = ks*32 + hr*8 + j;
                o[j] = (short)f2bf(eluf(xv*lp[c] + lp[128+c]));
            }
            B[ks] = o;
        }
        __builtin_amdgcn_sched_barrier(0);   // pin: h phase done before MFMA phase

        float y[8][4];
        #pragma unroll
        for (int ct=0; ct<8; ++ct){
            f32x4 a2 = {0.f,0.f,0.f,0.f}, ag = {0.f,0.f,0.f,0.f};
            const int wr = ct*16 + c16;
            #pragma unroll
            for (int ks=0;ks<4;++ks){
                int chunk = (ks*4 + hr) ^ (wr&7);
                s16x8 A2 = *reinterpret_cast<const s16x8*>(lw2 + wr*128 + chunk*8);
                a2 = MFMA(A2, B[ks], a2);
            }
            #pragma unroll
            for (int ks=0;ks<4;++ks){
                int chunk = (ks*4 + hr) ^ (wr&7);
                s16x8 Ag = *reinterpret_cast<const s16x8*>(lwg + wr*128 + chunk*8);
                ag = MFMA(Ag, B[ks], ag);
            }
            const int obb = ct*16 + hr*4;
            float4 b2v = *reinterpret_cast<const float4*>(&lp[256+obb]);
            float4 bgv = *reinterpret_cast<const float4*>(&lp[384+obb]);
            float4 wsv = *reinterpret_cast<const float4*>(&lp[512+obb]);
            float4 bsv = *reinterpret_cast<const float4*>(&lp[640+obb]);
            #pragma unroll
            for (int j=0;j<4;++j){
                float h2 = a2[j] + reinterpret_cast<const float*>(&b2v)[j];
                float gg = sigm(ag[j] + reinterpret_cast<const float*>(&bgv)[j]);
                float sk = xv*reinterpret_cast<const float*>(&wsv)[j]
                           + reinterpret_cast<const float*>(&bsv)[j];
                y[ct][j] = gg*h2 + (1.f-gg)*sk;
            }
            __builtin_amdgcn_sched_barrier(0);   // bound in-flight work to one ct
        }
        // wave-local LN over 128 dims of row n=c16
        float s = 0.f, q = 0.f;
        #pragma unroll
        for (int ct=0;ct<8;++ct)
            #pragma unroll
            for (int j=0;j<4;++j){ float yy = y[ct][j]; s += yy; q += yy*yy; }
        s += __shfl_xor(s, 16); s += __shfl_xor(s, 32);
        q += __shfl_xor(q, 16); q += __shfl_xor(q, 32);
        float mean = s*(1.f/ND);
        float inv  = rsqrtf(q*(1.f/ND) - mean*mean + 1e-5f);

        // normalize + pack + store fragment-native: per ctp, wave writes
        // 1KB contiguous (lane 16B at c16*32 + hr*8 elems)
        const int grp = blockIdx.x*16 + w + pass*8;
        u16* stkb = ws + OFF_STK + (size_t)v*SV_ELEMS + (size_t)grp*2048;
        #pragma unroll
        for (int ctp=0; ctp<4; ++ctp){
            s16x8 o;
            #pragma unroll
            for (int hh=0; hh<2; ++hh){
                int ct = ctp*2 + hh;
                const int obb = ct*16 + hr*4;
                float4 gm = *reinterpret_cast<const float4*>(&lp[768+obb]);
                float4 bt = *reinterpret_cast<const float4*>(&lp[896+obb]);
                #pragma unroll
                for (int j=0;j<4;++j){
                    float z = (y[ct][j]-mean)*inv*reinterpret_cast<const float*>(&gm)[j]
                              + reinterpret_cast<const float*>(&bt)[j];
                    o[hh*4+j] = (short)f2bf(z);
                }
            }
            *reinterpret_cast<s16x8*>(stkb + ctp*512 + c16*32 + hr*8) = o;
            __builtin_amdgcn_sched_barrier(0);
        }
        // no barrier: LDS is read-only in this loop
    }
}

// ---------------- Kernel B: softmax GRN + weighted sum (64 rows/blk) ----
// abuf layout: [vrel2][rg4][ctp4][n16][32], 16B-units swizzled u^=(n>>1)&3
__device__ __forceinline__ s16x8 ldA(const u16* abuf, int vrel, int rg, int ctp, int n, int hr){
    int base = (((vrel*4 + rg)*4 + ctp)*16 + n)*32;
    int fn = (n>>1)&3;
    int u0 = (hr&1)*2;
    int half = (hr>>1)*4;
    s16x4 lo = *reinterpret_cast<const s16x4*>(abuf + base + (((u0  )^fn)<<3) + half);
    s16x4 hi = *reinterpret_cast<const s16x4*>(abuf + base + (((u0+1)^fn)<<3) + half);
    s16x8 r;
    r[0]=lo[0]; r[1]=lo[1]; r[2]=lo[2]; r[3]=lo[3];
    r[4]=hi[0]; r[5]=hi[1]; r[6]=hi[2]; r[7]=hi[3];
    return r;
}

__global__ __launch_bounds__(512, 4)
void vsn_softB(const u16* __restrict__ ws,
               const float* __restrict__ sb1, const float* __restrict__ sb2,
               const float* __restrict__ sbg, const float* __restrict__ sbs,
               const float* __restrict__ sgamma, const float* __restrict__ sbeta,
               float* __restrict__ out_proc, float* __restrict__ out_w)
{
    __shared__ u16   abuf[16384];    // 32KB K-chunk (2 vars x 4 rowgrps)
    __shared__ u16   hsb[64*128];    // 16KB hs bf16, swizzled
    __shared__ float pps_[2*64*16];  // sks partials (2 k-halves)
    __shared__ float pph[64*16];
    __shared__ float ppg[64*16];
    __shared__ float sksf[64*16];
    __shared__ float wgtb[64*16];

    float* pps = pps_;

    const int t = threadIdx.x, w = t>>6, l = t&63;
    const int hr = l>>4, c16 = l&15;
    const int row0 = blockIdx.x * NRB;
    const int grp0 = row0 >> 4;
    const int orow = w*16 + c16;
    const int rgs = w & 3;        // sks row-group
    const int khf = w >> 2;       // sks k-half

    const u16* stk  = ws + OFF_STK;
    const u16* sW1b = ws + OFF_SW1;
    const u16* sWsb = ws + OFF_SWS;

    f32x4 accHs[4] = {{0,0,0,0},{0,0,0,0},{0,0,0,0},{0,0,0,0}};
    f32x4 accSk = {0,0,0,0};

    #pragma unroll 1
    for (int kt=0; kt<8; ++kt){
        // stage: linear copy of 2 vars x 4 rowgrps (16B units), swizzled dst
        #pragma unroll
        for (int i=0;i<4;++i){
            int cid = i*512 + t;          // [vrel1][rg2][ctp2][n4][u2] bits
            int vv  = kt*2 + (cid>>10);
            int n   = (cid>>2)&15;
            int u   = cid&3;
            const u16* src = stk + (size_t)vv*SV_ELEMS + (size_t)(grp0+((cid>>8)&3))*2048
                           + ((cid>>2)&63)*32 + u*8;
            s16x8 val = *reinterpret_cast<const s16x8*>(src);
            *reinterpret_cast<s16x8*>(abuf + (cid>>2)*32 + ((u ^ ((n>>1)&3))<<3)) = val;
        }
        __syncthreads();
        // hs GEMM: B-frag loaded once per ks, reused for 4 row-groups
        #pragma unroll
        for (int ks=0; ks<8; ++ks){
            s16x8 bf = *reinterpret_cast<const s16x8*>(
                sW1b + (size_t)orow*NVD + kt*256 + ks*32 + hr*8);
            #pragma unroll
            for (int rg=0; rg<4; ++rg){
                s16x8 af = ldA(abuf, ks>>2, rg, ks&3, c16, hr);
                accHs[rg] = MFMA(af, bf, accHs[rg]);
            }
        }
        // sks: wave covers (row-group rgs, k-half khf)
        #pragma unroll
        for (int kk=0; kk<4; ++kk){
            int ks = khf*4 + kk;
            s16x8 bf = *reinterpret_cast<const s16x8*>(
                sWsb + (size_t)c16*NVD + kt*256 + ks*32 + hr*8);
            s16x8 af = ldA(abuf, ks>>2, rgs, ks&3, c16, hr);
            accSk = MFMA(af, bf, accSk);
        }
        __syncthreads();
    }

    // epilogue: hs -> LDS ; sks partials
    {
        float bb = sb1[orow];
        #pragma unroll
        for (int rg=0; rg<4; ++rg){
            #pragma unroll
            for (int j=0;j<4;++j){
                int r = rg*16 + hr*4 + j;
                hsb[offHs(r, orow)] = (u16)f2bf(eluf(accHs[rg][j] + bb));
            }
        }
        #pragma unroll
        for (int j=0;j<4;++j)
            pps[khf*1024 + (rgs*16 + hr*4 + j)*16 + c16] = accSk[j];
    }
    __syncthreads();

    // sks reduce (+sbs)
    #pragma unroll
    for (int i=0;i<2;++i){
        int idx = i*512 + t;          // r*16+vv
        sksf[idx] = pps[idx] + pps[1024+idx] + sbs[idx&15];
    }
    // h2s/gs: waves 0-3 -> sW2 (rg=w), waves 4-7 -> sWg; full K in-reg
    {
        const u16* Bsrc = (w < 4) ? (ws + OFF_SW2) : (ws + OFF_SWG);
        int rg = w & 3;
        f32x4 acc = {0,0,0,0};
        #pragma unroll
        for (int ks=0; ks<4; ++ks){
            int rr = rg*16 + c16;
            int chunk = (ks*4 + hr) ^ (rr&7);
            s16x8 af = *reinterpret_cast<const s16x8*>(hsb + rr*128 + chunk*8);
            s16x8 bf = *reinterpret_cast<const s16x8*>(Bsrc + c16*ND + ks*32 + hr*8);
            acc = MFMA(af, bf, acc);
        }
        float* dst = (w < 4) ? pph : ppg;
        #pragma unroll
        for (int j=0;j<4;++j)
            dst[(rg*16 + hr*4 + j)*16 + c16] = acc[j];
    }
    __syncthreads();

    // gate-mix, LN over V, softmax -> weights (16 lanes per row)
    #pragma unroll
    for (int it=0; it<2; ++it){
        int r = it*32 + (t>>4), vv = t & 15;
        float h2s = pph[r*16+vv] + sb2[vv];
        float gs  = sigm(ppg[r*16+vv] + sbg[vv]);
        float yv  = gs*h2s + (1.f-gs)*sksf[r*16+vv];
        float ssum = yv, qsum = yv*yv;
        #pragma unroll
        for (int m=1;m<16;m<<=1){ ssum += __shfl_xor(ssum,m,16); qsum += __shfl_xor(qsum,m,16); }
        float mean = ssum*(1.f/NVAR);
        float var  = qsum*(1.f/NVAR) - mean*mean;
        float z = (yv-mean)*rsqrtf(var+1e-5f)*sgamma[vv] + sbeta[vv];
        float mx = z;
        #pragma unroll
        for (int m=1;m<16;m<<=1) mx = fmaxf(mx, __shfl_xor(mx,m,16));
        float e = __expf(z-mx);
        float es = e;
        #pragma unroll
        for (int m=1;m<16;m<<=1) es += __shfl_xor(es,m,16);
        float wgt = e * __builtin_amdgcn_rcpf(es);
        wgtb[r*16+vv] = wgt;
        out_w[(size_t)(row0+r)*NVAR + vv] = wgt;
    }
    __syncthreads();

    // processed = sum_v stacked * weights (fragment-native layout)
    #pragma unroll
    for (int it=0; it<2; ++it){
        int idx = it*512 + t;          // 0..1023
        int r = idx>>4, cu = idx&15;
        int ctp = cu>>2, u = cu&3;
        int grp = (row0+r)>>4, n = r&15;
        float acc[8] = {0,0,0,0,0,0,0,0};
        #pragma unroll
        for (int v=0; v<NVAR; ++v){
            float wv = wgtb[r*16 + v];
            const u16* sp = stk + (size_t)v*SV_ELEMS + (size_t)grp*2048
                          + (ctp*16+n)*32 + u*8;
            s16x8 sv = *reinterpret_cast<const s16x8*>(sp);
            #pragma unroll
            for (int k=0;k<8;++k) acc[k] += bf2f((u16)sv[k]) * wv;
        }
        // element k -> o = ctp*32 + (k>>2)*16 + u*4 + (k&3)
        float* op = out_proc + (size_t)(row0+r)*ND + ctp*32 + u*4;
        float4 lo = { acc[0], acc[1], acc[2], acc[3] };
        float4 hi = { acc[4], acc[5], acc[6], acc[7] };
        *reinterpret_cast<float4*>(op)      = lo;
        *reinterpret_cast<float4*>(op + 16) = hi;
    }
}

// ---------------- Fallback: fused kernel (verified R3 lineage) ----------
__global__ __launch_bounds__(512, 4)
void vsn_fused(const float* __restrict__ x,
               const float* __restrict__ W1, const float* __restrict__ b1,
               const float* __restrict__ b2, const float* __restrict__ bg,
               const float* __restrict__ Wsk, const float* __restrict__ bsk,
               const float* __restrict__ gamma, const float* __restrict__ beta,
               const float* __restrict__ sb1, const float* __restrict__ sb2,
               const float* __restrict__ sbg, const float* __restrict__ sbs,
               const float* __restrict__ sgamma, const float* __restrict__ sbeta,
               const u16* __restrict__ ws,
               float* __restrict__ out_proc, float* __restrict__ out_w)
{
    __shared__ u16   big[16*2048];
    __shared__ u16   hsb[16*128];
    __shared__ float pp[8*256];
    __shared__ float psumbuf[256];
    __shared__ float sksbuf[256];
    __shared__ float sx[256];

    float* psum  = psumbuf;
    float* psum2 = psumbuf + 128;

    const int t   = threadIdx.x;
    const int w   = t >> 6;
    const int l   = t & 63;
    const int hr  = l >> 4;
    const int c16 = l & 15;
    const int row0 = blockIdx.x * 16;
    const int orow = w*16 + c16;

    if (t < 256) sx[t] = x[row0*NVAR + t];
    __syncthreads();

    const u16* W2b = ws + OFF_W2;
    const u16* Wgb = ws + OFF_WG;

    for (int v = 0; v < NVAR; ++v){
        #pragma unroll
        for (int i = 0; i < 4; ++i){
            int idx = i*512 + t;
            int r = idx >> 7, d = idx & 127;
            float hv = eluf(sx[r*NVAR+v]*W1[v*ND+d] + b1[v*ND+d]);
            big[offBig(r, v*ND+d)] = (u16)f2bf(hv);
        }
        __syncthreads();

        s16x8 A[4];
        #pragma unroll
        for (int ks = 0; ks < 4; ++ks)
            A[ks] = *reinterpret_cast<const s16x8*>(&big[offBig(c16, v*ND + ks*32 + hr*8)]);
        const s16x8* B2p = reinterpret_cast<const s16x8*>(W2b + v*ND*ND + orow*ND + hr*8);
        const s16x8* Bgp = reinterpret_cast<const s16x8*>(Wgb + v*ND*ND + orow*ND + hr*8);
        f32x4 acc2 = {0.f,0.f,0.f,0.f}, accg = {0.f,0.f,0.f,0.f};
        #pragma unroll
        for (int ks = 0; ks < 4; ++ks) acc2 = MFMA(A[ks], B2p[ks*4], acc2);
        #pragma unroll
        for (int ks = 0; ks < 4; ++ks) accg = MFMA(A[ks], Bgp[ks*4], accg);

        const float b2v = b2[v*ND+orow], bgv = bg[v*ND+orow];
        const float wsv = Wsk[v*ND+orow], bsv = bsk[v*ND+orow];
        float y[4];
        #pragma unroll
        for (int j = 0; j < 4; ++j){
            int r = hr*4 + j;
            float h2 = acc2[j] + b2v;
            float g  = sigm(accg[j] + bgv);
            float sk = sx[r*NVAR+v]*wsv + bsv;
            y[j] = g*h2 + (1.f-g)*sk;
        }
        float s[4], q[4];
        #pragma unroll
        for (int j=0;j<4;++j){ s[j]=y[j]; q[j]=y[j]*y[j]; }
        #pragma unroll
        for (int m=1; m<16; m<<=1){
            #pragma unroll
            for (int j=0;j<4;++j){
                s[j] += __shfl_xor(s[j], m, 16);
                q[j] += __shfl_xor(q[j], m, 16);
            }
        }
        if (c16 == 0){
            #pragma unroll
            for (int j=0;j<4;++j){
                psum [(hr*4+j)*8 + w] = s[j];
                psum2[(hr*4+j)*8 + w] = q[j];
            }
        }
        __syncthreads();

        if (t < 16){
            float ss=0.f, qq=0.f;
            #pragma unroll
            for (int ww=0; ww<8; ++ww){ ss += psum[t*8+ww]; qq += psum2[t*8+ww]; }
            float mean = ss*(1.f/ND);
            float var  = qq*(1.f/ND) - mean*mean;
            sksbuf[t]      = mean;
            sksbuf[16 + t] = rsqrtf(var + 1e-5f);
        }
        __syncthreads();

        const float gm = gamma[v*ND+orow], bt = beta[v*ND+orow];
        #pragma unroll
        for (int j=0;j<4;++j){
            int r = hr*4 + j;
            float z = (y[j]-sksbuf[r])*sksbuf[16+r]*gm + bt;
            big[offBig(r, v*ND+orow)] = (u16)f2bf(z);
        }
    }
    __syncthreads();

    const u16* sW1b = ws + OFF_SW1;
    {
        f32x4 acc0 = {0,0,0,0}, acc1 = {0,0,0,0};
        const s16x8* Bp = reinterpret_cast<const s16x8*>(sW1b + orow*NVD + hr*8);
        #pragma unroll 8
        for (int ks = 0; ks < 64; ks += 2){
            s16x8 A0 = *reinterpret_cast<const s16x8*>(&big[offBig(c16, ks*32 + hr*8)]);
            s16x8 A1 = *reinterpret_cast<const s16x8*>(&big[offBig(c16, (ks+1)*32 + hr*8)]);
            acc0 = MFMA(A0, Bp[ks*4],     acc0);
            acc1 = MFMA(A1, Bp[(ks+1)*4], acc1);
        }
        float bb = sb1[orow];
        #pragma unroll
        for (int j=0;j<4;++j){
            int r = hr*4 + j;
            hsb[offHs(r, orow)] = (u16)f2bf(eluf(acc0[j] + acc1[j] + bb));
        }
    }
    const u16* sWsb = ws + OFF_SWS;
    {
        f32x4 acc = {0,0,0,0};
        const s16x8* Bp = reinterpret_cast<const s16x8*>(sWsb + c16*NVD + hr*8);
        #pragma unroll
        for (int kk = 0; kk < 8; ++kk){
            int ks = w*8 + kk;
            s16x8 Af = *reinterpret_cast<const s16x8*>(&big[offBig(c16, ks*32 + hr*8)]);
            acc = MFMA(Af, Bp[ks*4], acc);
        }
        #pragma unroll
        for (int j=0;j<4;++j)
            pp[w*256 + (hr*4+j)*16 + c16] = acc[j];
    }
    __syncthreads();

    if (t < 256){
        float a = sbs[t & 15];
        #pragma unroll
        for (int ww=0; ww<8; ++ww) a += pp[ww*256 + t];
        sksbuf[t] = a;
    }
    __syncthreads();

    {
        const u16* Bsrc = (w < 4) ? (ws + OFF_SW2) : (ws + OFF_SWG);
        const int m = w & 3;
        s16x8 Af = *reinterpret_cast<const s16x8*>(&hsb[offHs(c16, m*32 + hr*8)]);
        s16x8 Bf = *reinterpret_cast<const s16x8*>(Bsrc + c16*ND + m*32 + hr*8);
        f32x4 z4 = {0,0,0,0};
        f32x4 acc = MFMA(Af, Bf, z4);
        #pragma unroll
        for (int j=0;j<4;++j)
            pp[w*256 + (hr*4+j)*16 + c16] = acc[j];
    }
    __syncthreads();

    if (t < 256){
        int r = t >> 4, vv = t & 15;
        float h2s = sb2[vv], gp = sbg[vv];
        #pragma unroll
        for (int j=0;j<4;++j){ h2s += pp[j*256 + t]; gp += pp[(4+j)*256 + t]; }
        float gs = sigm(gp);
        float yv = gs*h2s + (1.f-gs)*sksbuf[t];
        float ssum = yv, qsum = yv*yv;
        #pragma unroll
        for (int m=1;m<16;m<<=1){ ssum += __shfl_xor(ssum,m,16); qsum += __shfl_xor(qsum,m,16); }
        float mean = ssum*(1.f/NVAR);
        float var  = qsum*(1.f/NVAR) - mean*mean;
        float z = (yv-mean)*rsqrtf(var+1e-5f)*sgamma[vv] + sbeta[vv];
        float mx = z;
        #pragma unroll
        for (int m=1;m<16;m<<=1) mx = fmaxf(mx, __shfl_xor(mx,m,16));
        float e = __expf(z-mx);
        float es = e;
        #pragma unroll
        for (int m=1;m<16;m<<=1) es += __shfl_xor(es,m,16);
        float wgt = e/es;
        psumbuf[t] = wgt;
        out_w[(row0+r)*NVAR + vv] = wgt;
    }
    __syncthreads();

    if (t < 256){
        int r = t >> 4, d8 = (t & 15)*8;
        float acc[8] = {0,0,0,0,0,0,0,0};
        #pragma unroll
        for (int v=0; v<NVAR; ++v){
            float wv = psumbuf[r*NVAR + v];
            s16x8 sv = *reinterpret_cast<const s16x8*>(&big[offBig(r, v*ND + d8)]);
            #pragma unroll
            for (int k=0;k<8;++k) acc[k] += bf2f((u16)sv[k]) * wv;
        }
        float* op = &out_proc[(row0+r)*ND + d8];
        #pragma unroll
        for (int k=0;k<8;++k) op[k] = acc[k];
    }
}

extern "C" void kernel_launch(void* const* d_in, const int* in_sizes, int n_in,
                              void* d_out, int out_size, void* d_ws, size_t ws_size,
                              hipStream_t stream) {
    (void)in_sizes; (void)n_in; (void)out_size;
    const float* x     = (const float*)d_in[0];
    const float* W1    = (const float*)d_in[1];
    const float* b1    = (const float*)d_in[2];
    const float* W2    = (const float*)d_in[3];
    const float* b2    = (const float*)d_in[4];
    const float* Wg    = (const float*)d_in[5];
    const float* bg    = (const float*)d_in[6];
    const float* Wsk   = (const float*)d_in[7];
    const float* bsk   = (const float*)d_in[8];
    const float* gamma = (const float*)d_in[9];
    const float* beta  = (const float*)d_in[10];
    const float* sW1   = (const float*)d_in[11];
    const float* sb1   = (const float*)d_in[12];
    const float* sW2   = (const float*)d_in[13];
    const float* sb2   = (const float*)d_in[14];
    const float* sWg   = (const float*)d_in[15];
    const float* sbg   = (const float*)d_in[16];
    const float* sWs   = (const float*)d_in[17];
    const float* sbs   = (const float*)d_in[18];
    const float* sgam  = (const float*)d_in[19];
    const float* sbet  = (const float*)d_in[20];

    u16* ws = (u16*)d_ws;
    float* out_proc = (float*)d_out;
    float* out_w    = out_proc + (size_t)NROWS * ND;

    prep_kernel<<<(WS_ELEMS + 255)/256, 256, 0, stream>>>(W2, Wg, sW1, sWs, sW2, sWg, ws);

    if (ws_size >= WS_NEEDED_BYTES) {
        vsn_varA<<<dim3(NROWS/RTA, NVAR), 512, 0, stream>>>(
            x, W1, b1, b2, bg, Wsk, bsk, gamma, beta, ws);
        vsn_softB<<<NROWS/NRB, 512, 0, stream>>>(
            ws, sb1, sb2, sbg, sbs, sgam, sbet, out_proc, out_w);
    } else {
        vsn_fused<<<NROWS/16, 512, 0, stream>>>(
            x, W1, b1, b2, bg, Wsk, bsk, gamma, beta,
            sb1, sb2, sbg, sbs, sgam, sbet, ws, out_proc, out_w);
    }
}

// Round 12
// 108.779 us; speedup vs baseline: 4.2042x; 1.0157x over previous
//
#include <hip/hip_runtime.h>
#include <hip/hip_bf16.h>
#include <math.h>

// VSN: B=32,T=512,V=16,D=128. prep (weights->bf16), varA (per-var GRN,
// h-in-registers, fragment-native stacked layout, sched_barrier-pinned),
// softB (32-row blocks -> 2 blocks/CU). Fallback: fused kernel.
#define NVAR 16
#define ND 128
#define NVD 2048
#define NROWS 16384
#define RTA 256          // rows per varA block
#define NRB 32           // rows per softB block

typedef short s16x8 __attribute__((ext_vector_type(8)));
typedef short s16x4 __attribute__((ext_vector_type(4)));
typedef float f32x4 __attribute__((ext_vector_type(4)));
typedef unsigned short u16;

#define MFMA(a,b,c) __builtin_amdgcn_mfma_f32_16x16x32_bf16((a),(b),(c),0,0,0)

// ws layout (u16 units)
#define OFF_W2  0
#define OFF_WG  262144
#define OFF_SW1 524288
#define OFF_SWS 786432
#define OFF_SW2 819200
#define OFF_SWG 821248
#define WS_ELEMS 823296
#define OFF_STK 823296
#define STK_ELEMS ((size_t)NROWS*NVD)
#define WS_NEEDED_BYTES (((size_t)WS_ELEMS + STK_ELEMS)*2)
// stacked fragment-native layout: stk[v][rowgrp][ctp 4][n 16][32 elems]
#define SV_ELEMS ((size_t)(NROWS/16)*2048)

// manual RNE f32->bf16 (pure ALU; __float2bfloat16 + addr-cast allocas -> spill, R8)
__device__ __forceinline__ unsigned f2bf(float f){
    union { float f; unsigned u; } c; c.f = f;
    unsigned u = c.u;
    u += 0x7fffu + ((u >> 16) & 1u);
    return u >> 16;
}
__device__ __forceinline__ float bf2f(unsigned bits){
    union { unsigned u; float f; } c; c.u = bits << 16;
    return c.f;
}
// fast ELU / sigmoid: single v_exp_f32 each
__device__ __forceinline__ float eluf(float x){ return x > 0.f ? x : __expf(x) - 1.f; }
__device__ __forceinline__ float sigm(float x){
    return __builtin_amdgcn_rcpf(1.f + __expf(-x));
}

__device__ __forceinline__ int offHs(int r, int c){
    return r*128 + ((((c>>3) ^ (r&7))<<3) | (c&7));
}
__device__ __forceinline__ int offBig(int r, int c){
    return r*2048 + ((((c>>3) ^ (r&7))<<3) | (c&7));
}

__global__ void prep_kernel(const float* __restrict__ W2, const float* __restrict__ Wg,
                            const float* __restrict__ sW1, const float* __restrict__ sWs,
                            const float* __restrict__ sW2, const float* __restrict__ sWg,
                            u16* __restrict__ ws){
    int i = blockIdx.x*256 + threadIdx.x;
    if (i >= WS_ELEMS) return;
    float v;
    if      (i < OFF_WG)  v = W2[i];
    else if (i < OFF_SW1) v = Wg[i-OFF_WG];
    else if (i < OFF_SWS) v = sW1[i-OFF_SW1];
    else if (i < OFF_SW2) v = sWs[i-OFF_SWS];
    else if (i < OFF_SWG) v = sW2[i-OFF_SW2];
    else                  v = sWg[i-OFF_SWG];
    ws[i] = (u16)f2bf(v);
}

// ---------------- Kernel A: per-var GRN -> stacked bf16 (R11-verified) ---
__global__ __launch_bounds__(512, 2)
void vsn_varA(const float* __restrict__ x,
              const float* __restrict__ W1, const float* __restrict__ b1,
              const float* __restrict__ b2, const float* __restrict__ bg,
              const float* __restrict__ Wsk, const float* __restrict__ bsk,
              const float* __restrict__ gamma, const float* __restrict__ beta,
              u16* __restrict__ ws)
{
    __shared__ u16 lw2[128*128];     // 32KB, swizzled
    __shared__ u16 lwg[128*128];     // 32KB, swizzled
    __shared__ float lp[8*128];      // W1,b1,b2,bg,Ws,bs,gamma,beta (4KB)
    __shared__ float lxv[RTA];       // x[:, v] (1KB)

    const int t = threadIdx.x, w = t>>6, l = t&63;
    const int hr = l>>4, c16 = l&15;
    const int v = blockIdx.y;
    const int row0 = blockIdx.x*RTA;

    #pragma unroll
    for (int i=0;i<8;++i){
        int cid = i*512 + t;
        int mat = cid>>11, within = cid&2047;
        int r = within>>4, c8 = within&15;
        const u16* src = ws + (mat? OFF_WG:OFF_W2) + v*16384 + r*128 + c8*8;
        s16x8 val = *reinterpret_cast<const s16x8*>(src);
        u16* dst = (mat? lwg:lw2) + r*128 + ((c8 ^ (r&7))<<3);
        *reinterpret_cast<s16x8*>(dst) = val;
    }
    if (t < 128){
        lp[t]     = W1[v*ND+t];    lp[128+t] = b1[v*ND+t];
        lp[256+t] = b2[v*ND+t];    lp[384+t] = bg[v*ND+t];
        lp[512+t] = Wsk[v*ND+t];   lp[640+t] = bsk[v*ND+t];
        lp[768+t] = gamma[v*ND+t]; lp[896+t] = beta[v*ND+t];
    }
    if (t < RTA) lxv[t] = x[(size_t)(row0+t)*NVAR + v];
    __syncthreads();

    #pragma unroll 1
    for (int pass=0; pass<2; ++pass){
        const int lrow0 = (w + pass*8)*16;
        const float xv = lxv[lrow0 + c16];

        s16x8 B[4];
        #pragma unroll
        for (int ks=0;ks<4;++ks){
            s16x8 o;
            #pragma unroll
            for (int j=0;j<8;++j){
                int c = ks*32 + hr*8 + j;
                o[j] = (short)f2bf(eluf(xv*lp[c] + lp[128+c]));
            }
            B[ks] = o;
        }
        __builtin_amdgcn_sched_barrier(0);

        float y[8][4];
        #pragma unroll
        for (int ct=0; ct<8; ++ct){
            f32x4 a2 = {0.f,0.f,0.f,0.f}, ag = {0.f,0.f,0.f,0.f};
            const int wr = ct*16 + c16;
            #pragma unroll
            for (int ks=0;ks<4;++ks){
                int chunk = (ks*4 + hr) ^ (wr&7);
                s16x8 A2 = *reinterpret_cast<const s16x8*>(lw2 + wr*128 + chunk*8);
                a2 = MFMA(A2, B[ks], a2);
            }
            #pragma unroll
            for (int ks=0;ks<4;++ks){
                int chunk = (ks*4 + hr) ^ (wr&7);
                s16x8 Ag = *reinterpret_cast<const s16x8*>(lwg + wr*128 + chunk*8);
                ag = MFMA(Ag, B[ks], ag);
            }
            const int obb = ct*16 + hr*4;
            float4 b2v = *reinterpret_cast<const float4*>(&lp[256+obb]);
            float4 bgv = *reinterpret_cast<const float4*>(&lp[384+obb]);
            float4 wsv = *reinterpret_cast<const float4*>(&lp[512+obb]);
            float4 bsv = *reinterpret_cast<const float4*>(&lp[640+obb]);
            #pragma unroll
            for (int j=0;j<4;++j){
                float h2 = a2[j] + reinterpret_cast<const float*>(&b2v)[j];
                float gg = sigm(ag[j] + reinterpret_cast<const float*>(&bgv)[j]);
                float sk = xv*reinterpret_cast<const float*>(&wsv)[j]
                           + reinterpret_cast<const float*>(&bsv)[j];
                y[ct][j] = gg*h2 + (1.f-gg)*sk;
            }
            __builtin_amdgcn_sched_barrier(0);
        }
        float s = 0.f, q = 0.f;
        #pragma unroll
        for (int ct=0;ct<8;++ct)
            #pragma unroll
            for (int j=0;j<4;++j){ float yy = y[ct][j]; s += yy; q += yy*yy; }
        s += __shfl_xor(s, 16); s += __shfl_xor(s, 32);
        q += __shfl_xor(q, 16); q += __shfl_xor(q, 32);
        float mean = s*(1.f/ND);
        float inv  = rsqrtf(q*(1.f/ND) - mean*mean + 1e-5f);

        const int grp = blockIdx.x*16 + w + pass*8;
        u16* stkb = ws + OFF_STK + (size_t)v*SV_ELEMS + (size_t)grp*2048;
        #pragma unroll
        for (int ctp=0; ctp<4; ++ctp){
            s16x8 o;
            #pragma unroll
            for (int hh=0; hh<2; ++hh){
                int ct = ctp*2 + hh;
                const int obb = ct*16 + hr*4;
                float4 gm = *reinterpret_cast<const float4*>(&lp[768+obb]);
                float4 bt = *reinterpret_cast<const float4*>(&lp[896+obb]);
                #pragma unroll
                for (int j=0;j<4;++j){
                    float z = (y[ct][j]-mean)*inv*reinterpret_cast<const float*>(&gm)[j]
                              + reinterpret_cast<const float*>(&bt)[j];
                    o[hh*4+j] = (short)f2bf(z);
                }
            }
            *reinterpret_cast<s16x8*>(stkb + ctp*512 + c16*32 + hr*8) = o;
            __builtin_amdgcn_sched_barrier(0);
        }
    }
}

// ---------------- Kernel B: softmax GRN + weighted sum (32 rows/blk) ----
// abuf layout: [vrel2][rg2][ctp4][n16][32], 16B-units swizzled u^=(n>>1)&3
__device__ __forceinline__ s16x8 ldA(const u16* abuf, int vrel, int rg, int ctp, int n, int hr){
    int base = (((vrel*2 + rg)*4 + ctp)*16 + n)*32;
    int fn = (n>>1)&3;
    int u0 = (hr&1)*2;
    int half = (hr>>1)*4;
    s16x4 lo = *reinterpret_cast<const s16x4*>(abuf + base + (((u0  )^fn)<<3) + half);
    s16x4 hi = *reinterpret_cast<const s16x4*>(abuf + base + (((u0+1)^fn)<<3) + half);
    s16x8 r;
    r[0]=lo[0]; r[1]=lo[1]; r[2]=lo[2]; r[3]=lo[3];
    r[4]=hi[0]; r[5]=hi[1]; r[6]=hi[2]; r[7]=hi[3];
    return r;
}

__global__ __launch_bounds__(512, 4)
void vsn_softB(const u16* __restrict__ ws,
               const float* __restrict__ sb1, const float* __restrict__ sb2,
               const float* __restrict__ sbg, const float* __restrict__ sbs,
               const float* __restrict__ sgamma, const float* __restrict__ sbeta,
               float* __restrict__ out_proc, float* __restrict__ out_w)
{
    __shared__ u16   abuf[8192];     // 16KB K-chunk (2 vars x 2 rowgrps)
    __shared__ u16   hsb[32*128];    // 8KB hs bf16, swizzled
    __shared__ float pps_[4*32*16];  // 8KB sks partials (4 k-quarters)
    __shared__ float pph[32*16];
    __shared__ float ppg[32*16];
    __shared__ float sksf[32*16];
    __shared__ float wgtb[32*16];

    float* pps = pps_;

    const int t = threadIdx.x, w = t>>6, l = t&63;
    const int hr = l>>4, c16 = l&15;
    const int row0 = blockIdx.x * NRB;
    const int grp0 = row0 >> 4;       // 2 rowgroups per block
    const int orow = w*16 + c16;
    const int rgs = w & 1;            // sks row-group
    const int khf = w >> 1;           // sks k-quarter (0..3)

    const u16* stk  = ws + OFF_STK;
    const u16* sW1b = ws + OFF_SW1;
    const u16* sWsb = ws + OFF_SWS;

    f32x4 accHs[2] = {{0,0,0,0},{0,0,0,0}};
    f32x4 accSk = {0,0,0,0};

    #pragma unroll 1
    for (int kt=0; kt<8; ++kt){
        // stage: 2 vars x 2 rowgrps = 1024 16B-chunks, swizzled dst
        #pragma unroll
        for (int i=0;i<2;++i){
            int cid = i*512 + t;          // vrel(1)|rg(1)|ctp(2)|n(4)|u(2)
            int vv  = kt*2 + (cid>>9);
            int rg  = (cid>>8)&1;
            int n   = (cid>>2)&15;
            int u   = cid&3;
            const u16* src = stk + (size_t)vv*SV_ELEMS + (size_t)(grp0+rg)*2048
                           + ((cid>>2)&63)*32 + u*8;
            s16x8 val = *reinterpret_cast<const s16x8*>(src);
            *reinterpret_cast<s16x8*>(abuf + (cid>>2)*32 + ((u ^ ((n>>1)&3))<<3)) = val;
        }
        __syncthreads();
        // hs GEMM: B-frag loaded once per ks, reused for 2 row-groups
        #pragma unroll
        for (int ks=0; ks<8; ++ks){
            s16x8 bf = *reinterpret_cast<const s16x8*>(
                sW1b + (size_t)orow*NVD + kt*256 + ks*32 + hr*8);
            #pragma unroll
            for (int rg=0; rg<2; ++rg){
                s16x8 af = ldA(abuf, ks>>2, rg, ks&3, c16, hr);
                accHs[rg] = MFMA(af, bf, accHs[rg]);
            }
        }
        // sks: wave covers (row-group rgs, k-quarter khf)
        #pragma unroll
        for (int kk=0; kk<2; ++kk){
            int ks = khf*2 + kk;
            s16x8 bf = *reinterpret_cast<const s16x8*>(
                sWsb + (size_t)c16*NVD + kt*256 + ks*32 + hr*8);
            s16x8 af = ldA(abuf, ks>>2, rgs, ks&3, c16, hr);
            accSk = MFMA(af, bf, accSk);
        }
        __syncthreads();
    }

    // epilogue: hs -> LDS ; sks partials
    {
        float bb = sb1[orow];
        #pragma unroll
        for (int rg=0; rg<2; ++rg){
            #pragma unroll
            for (int j=0;j<4;++j){
                int r = rg*16 + hr*4 + j;
                hsb[offHs(r, orow)] = (u16)f2bf(eluf(accHs[rg][j] + bb));
            }
        }
        #pragma unroll
        for (int j=0;j<4;++j)
            pps[khf*512 + (rgs*16 + hr*4 + j)*16 + c16] = accSk[j];
    }
    __syncthreads();

    // sks reduce (+sbs): 512 elems, all threads
    sksf[t] = pps[t] + pps[512+t] + pps[1024+t] + pps[1536+t] + sbs[t&15];
    // h2s/gs: waves 0-1 -> sW2 (rg=w), waves 2-3 -> sWg (rg=w-2); full K in-reg
    if (w < 4){
        const u16* Bsrc = (w < 2) ? (ws + OFF_SW2) : (ws + OFF_SWG);
        int rg = w & 1;
        f32x4 acc = {0,0,0,0};
        #pragma unroll
        for (int ks=0; ks<4; ++ks){
            int rr = rg*16 + c16;
            int chunk = (ks*4 + hr) ^ (rr&7);
            s16x8 af = *reinterpret_cast<const s16x8*>(hsb + rr*128 + chunk*8);
            s16x8 bf = *reinterpret_cast<const s16x8*>(Bsrc + c16*ND + ks*32 + hr*8);
            acc = MFMA(af, bf, acc);
        }
        float* dst = (w < 2) ? pph : ppg;
        #pragma unroll
        for (int j=0;j<4;++j)
            dst[(rg*16 + hr*4 + j)*16 + c16] = acc[j];
    }
    __syncthreads();

    // gate-mix, LN over V, softmax -> weights (16 lanes per row; 32 rows)
    {
        int r = t>>4, vv = t & 15;
        float h2s = pph[r*16+vv] + sb2[vv];
        float gs  = sigm(ppg[r*16+vv] + sbg[vv]);
        float yv  = gs*h2s + (1.f-gs)*sksf[r*16+vv];
        float ssum = yv, qsum = yv*yv;
        #pragma unroll
        for (int m=1;m<16;m<<=1){ ssum += __shfl_xor(ssum,m,16); qsum += __shfl_xor(qsum,m,16); }
        float mean = ssum*(1.f/NVAR);
        float var  = qsum*(1.f/NVAR) - mean*mean;
        float z = (yv-mean)*rsqrtf(var+1e-5f)*sgamma[vv] + sbeta[vv];
        float mx = z;
        #pragma unroll
        for (int m=1;m<16;m<<=1) mx = fmaxf(mx, __shfl_xor(mx,m,16));
        float e = __expf(z-mx);
        float es = e;
        #pragma unroll
        for (int m=1;m<16;m<<=1) es += __shfl_xor(es,m,16);
        float wgt = e * __builtin_amdgcn_rcpf(es);
        wgtb[r*16+vv] = wgt;
        out_w[(size_t)(row0+r)*NVAR + vv] = wgt;
    }
    __syncthreads();

    // processed = sum_v stacked * weights (fragment-native layout; 32 rows)
    {
        int r = t>>4, cu = t&15;
        int ctp = cu>>2, u = cu&3;
        int grp = (row0+r)>>4, n = r&15;
        float acc[8] = {0,0,0,0,0,0,0,0};
        #pragma unroll
        for (int v=0; v<NVAR; ++v){
            float wv = wgtb[r*16 + v];
            const u16* sp = stk + (size_t)v*SV_ELEMS + (size_t)grp*2048
                          + (ctp*16+n)*32 + u*8;
            s16x8 sv = *reinterpret_cast<const s16x8*>(sp);
            #pragma unroll
            for (int k=0;k<8;++k) acc[k] += bf2f((u16)sv[k]) * wv;
        }
        float* op = out_proc + (size_t)(row0+r)*ND + ctp*32 + u*4;
        float4 lo = { acc[0], acc[1], acc[2], acc[3] };
        float4 hi = { acc[4], acc[5], acc[6], acc[7] };
        *reinterpret_cast<float4*>(op)      = lo;
        *reinterpret_cast<float4*>(op + 16) = hi;
    }
}

// ---------------- Fallback: fused kernel (verified R3 lineage) ----------
__global__ __launch_bounds__(512, 4)
void vsn_fused(const float* __restrict__ x,
               const float* __restrict__ W1, const float* __restrict__ b1,
               const float* __restrict__ b2, const float* __restrict__ bg,
               const float* __restrict__ Wsk, const float* __restrict__ bsk,
               const float* __restrict__ gamma, const float* __restrict__ beta,
               const float* __restrict__ sb1, const float* __restrict__ sb2,
               const float* __restrict__ sbg, const float* __restrict__ sbs,
               const float* __restrict__ sgamma, const float* __restrict__ sbeta,
               const u16* __restrict__ ws,
               float* __restrict__ out_proc, float* __restrict__ out_w)
{
    __shared__ u16   big[16*2048];
    __shared__ u16   hsb[16*128];
    __shared__ float pp[8*256];
    __shared__ float psumbuf[256];
    __shared__ float sksbuf[256];
    __shared__ float sx[256];

    float* psum  = psumbuf;
    float* psum2 = psumbuf + 128;

    const int t   = threadIdx.x;
    const int w   = t >> 6;
    const int l   = t & 63;
    const int hr  = l >> 4;
    const int c16 = l & 15;
    const int row0 = blockIdx.x * 16;
    const int orow = w*16 + c16;

    if (t < 256) sx[t] = x[row0*NVAR + t];
    __syncthreads();

    const u16* W2b = ws + OFF_W2;
    const u16* Wgb = ws + OFF_WG;

    for (int v = 0; v < NVAR; ++v){
        #pragma unroll
        for (int i = 0; i < 4; ++i){
            int idx = i*512 + t;
            int r = idx >> 7, d = idx & 127;
            float hv = eluf(sx[r*NVAR+v]*W1[v*ND+d] + b1[v*ND+d]);
            big[offBig(r, v*ND+d)] = (u16)f2bf(hv);
        }
        __syncthreads();

        s16x8 A[4];
        #pragma unroll
        for (int ks = 0; ks < 4; ++ks)
            A[ks] = *reinterpret_cast<const s16x8*>(&big[offBig(c16, v*ND + ks*32 + hr*8)]);
        const s16x8* B2p = reinterpret_cast<const s16x8*>(W2b + v*ND*ND + orow*ND + hr*8);
        const s16x8* Bgp = reinterpret_cast<const s16x8*>(Wgb + v*ND*ND + orow*ND + hr*8);
        f32x4 acc2 = {0.f,0.f,0.f,0.f}, accg = {0.f,0.f,0.f,0.f};
        #pragma unroll
        for (int ks = 0; ks < 4; ++ks) acc2 = MFMA(A[ks], B2p[ks*4], acc2);
        #pragma unroll
        for (int ks = 0; ks < 4; ++ks) accg = MFMA(A[ks], Bgp[ks*4], accg);

        const float b2v = b2[v*ND+orow], bgv = bg[v*ND+orow];
        const float wsv = Wsk[v*ND+orow], bsv = bsk[v*ND+orow];
        float y[4];
        #pragma unroll
        for (int j = 0; j < 4; ++j){
            int r = hr*4 + j;
            float h2 = acc2[j] + b2v;
            float g  = sigm(accg[j] + bgv);
            float sk = sx[r*NVAR+v]*wsv + bsv;
            y[j] = g*h2 + (1.f-g)*sk;
        }
        float s[4], q[4];
        #pragma unroll
        for (int j=0;j<4;++j){ s[j]=y[j]; q[j]=y[j]*y[j]; }
        #pragma unroll
        for (int m=1; m<16; m<<=1){
            #pragma unroll
            for (int j=0;j<4;++j){
                s[j] += __shfl_xor(s[j], m, 16);
                q[j] += __shfl_xor(q[j], m, 16);
            }
        }
        if (c16 == 0){
            #pragma unroll
            for (int j=0;j<4;++j){
                psum [(hr*4+j)*8 + w] = s[j];
                psum2[(hr*4+j)*8 + w] = q[j];
            }
        }
        __syncthreads();

        if (t < 16){
            float ss=0.f, qq=0.f;
            #pragma unroll
            for (int ww=0; ww<8; ++ww){ ss += psum[t*8+ww]; qq += psum2[t*8+ww]; }
            float mean = ss*(1.f/ND);
            float var  = qq*(1.f/ND) - mean*mean;
            sksbuf[t]      = mean;
            sksbuf[16 + t] = rsqrtf(var + 1e-5f);
        }
        __syncthreads();

        const float gm = gamma[v*ND+orow], bt = beta[v*ND+orow];
        #pragma unroll
        for (int j=0;j<4;++j){
            int r = hr*4 + j;
            float z = (y[j]-sksbuf[r])*sksbuf[16+r]*gm + bt;
            big[offBig(r, v*ND+orow)] = (u16)f2bf(z);
        }
    }
    __syncthreads();

    const u16* sW1b = ws + OFF_SW1;
    {
        f32x4 acc0 = {0,0,0,0}, acc1 = {0,0,0,0};
        const s16x8* Bp = reinterpret_cast<const s16x8*>(sW1b + orow*NVD + hr*8);
        #pragma unroll 8
        for (int ks = 0; ks < 64; ks += 2){
            s16x8 A0 = *reinterpret_cast<const s16x8*>(&big[offBig(c16, ks*32 + hr*8)]);
            s16x8 A1 = *reinterpret_cast<const s16x8*>(&big[offBig(c16, (ks+1)*32 + hr*8)]);
            acc0 = MFMA(A0, Bp[ks*4],     acc0);
            acc1 = MFMA(A1, Bp[(ks+1)*4], acc1);
        }
        float bb = sb1[orow];
        #pragma unroll
        for (int j=0;j<4;++j){
            int r = hr*4 + j;
            hsb[offHs(r, orow)] = (u16)f2bf(eluf(acc0[j] + acc1[j] + bb));
        }
    }
    const u16* sWsb = ws + OFF_SWS;
    {
        f32x4 acc = {0,0,0,0};
        const s16x8* Bp = reinterpret_cast<const s16x8*>(sWsb + c16*NVD + hr*8);
        #pragma unroll
        for (int kk = 0; kk < 8; ++kk){
            int ks = w*8 + kk;
            s16x8 Af = *reinterpret_cast<const s16x8*>(&big[offBig(c16, ks*32 + hr*8)]);
            acc = MFMA(Af, Bp[ks*4], acc);
        }
        #pragma unroll
        for (int j=0;j<4;++j)
            pp[w*256 + (hr*4+j)*16 + c16] = acc[j];
    }
    __syncthreads();

    if (t < 256){
        float a = sbs[t & 15];
        #pragma unroll
        for (int ww=0; ww<8; ++ww) a += pp[ww*256 + t];
        sksbuf[t] = a;
    }
    __syncthreads();

    {
        const u16* Bsrc = (w < 4) ? (ws + OFF_SW2) : (ws + OFF_SWG);
        const int m = w & 3;
        s16x8 Af = *reinterpret_cast<const s16x8*>(&hsb[offHs(c16, m*32 + hr*8)]);
        s16x8 Bf = *reinterpret_cast<const s16x8*>(Bsrc + c16*ND + m*32 + hr*8);
        f32x4 z4 = {0,0,0,0};
        f32x4 acc = MFMA(Af, Bf, z4);
        #pragma unroll
        for (int j=0;j<4;++j)
            pp[w*256 + (hr*4+j)*16 + c16] = acc[j];
    }
    __syncthreads();

    if (t < 256){
        int r = t >> 4, vv = t & 15;
        float h2s = sb2[vv], gp = sbg[vv];
        #pragma unroll
        for (int j=0;j<4;++j){ h2s += pp[j*256 + t]; gp += pp[(4+j)*256 + t]; }
        float gs = sigm(gp);
        float yv = gs*h2s + (1.f-gs)*sksbuf[t];
        float ssum = yv, qsum = yv*yv;
        #pragma unroll
        for (int m=1;m<16;m<<=1){ ssum += __shfl_xor(ssum,m,16); qsum += __shfl_xor(qsum,m,16); }
        float mean = ssum*(1.f/NVAR);
        float var  = qsum*(1.f/NVAR) - mean*mean;
        float z = (yv-mean)*rsqrtf(var+1e-5f)*sgamma[vv] + sbeta[vv];
        float mx = z;
        #pragma unroll
        for (int m=1;m<16;m<<=1) mx = fmaxf(mx, __shfl_xor(mx,m,16));
        float e = __expf(z-mx);
        float es = e;
        #pragma unroll
        for (int m=1;m<16;m<<=1) es += __shfl_xor(es,m,16);
        float wgt = e/es;
        psumbuf[t] = wgt;
        out_w[(row0+r)*NVAR + vv] = wgt;
    }
    __syncthreads();

    if (t < 256){
        int r = t >> 4, d8 = (t & 15)*8;
        float acc[8] = {0,0,0,0,0,0,0,0};
        #pragma unroll
        for (int v=0; v<NVAR; ++v){
            float wv = psumbuf[r*NVAR + v];
            s16x8 sv = *reinterpret_cast<const s16x8*>(&big[offBig(r, v*ND + d8)]);
            #pragma unroll
            for (int k=0;k<8;++k) acc[k] += bf2f((u16)sv[k]) * wv;
        }
        float* op = &out_proc[(row0+r)*ND + d8];
        #pragma unroll
        for (int k=0;k<8;++k) op[k] = acc[k];
    }
}

extern "C" void kernel_launch(void* const* d_in, const int* in_sizes, int n_in,
                              void* d_out, int out_size, void* d_ws, size_t ws_size,
                              hipStream_t stream) {
    (void)in_sizes; (void)n_in; (void)out_size;
    const float* x     = (const float*)d_in[0];
    const float* W1    = (const float*)d_in[1];
    const float* b1    = (const float*)d_in[2];
    const float* W2    = (const float*)d_in[3];
    const float* b2    = (const float*)d_in[4];
    const float* Wg    = (const float*)d_in[5];
    const float* bg    = (const float*)d_in[6];
    const float* Wsk   = (const float*)d_in[7];
    const float* bsk   = (const float*)d_in[8];
    const float* gamma = (const float*)d_in[9];
    const float* beta  = (const float*)d_in[10];
    const float* sW1   = (const float*)d_in[11];
    const float* sb1   = (const float*)d_in[12];
    const float* sW2   = (const float*)d_in[13];
    const float* sb2   = (const float*)d_in[14];
    const float* sWg   = (const float*)d_in[15];
    const float* sbg   = (const float*)d_in[16];
    const float* sWs   = (const float*)d_in[17];
    const float* sbs   = (const float*)d_in[18];
    const float* sgam  = (const float*)d_in[19];
    const float* sbet  = (const float*)d_in[20];

    u16* ws = (u16*)d_ws;
    float* out_proc = (float*)d_out;
    float* out_w    = out_proc + (size_t)NROWS * ND;

    prep_kernel<<<(WS_ELEMS + 255)/256, 256, 0, stream>>>(W2, Wg, sW1, sWs, sW2, sWg, ws);

    if (ws_size >= WS_NEEDED_BYTES) {
        vsn_varA<<<dim3(NROWS/RTA, NVAR), 512, 0, stream>>>(
            x, W1, b1, b2, bg, Wsk, bsk, gamma, beta, ws);
        vsn_softB<<<NROWS/NRB, 512, 0, stream>>>(
            ws, sb1, sb2, sbg, sbs, sgam, sbet, out_proc, out_w);
    } else {
        vsn_fused<<<NROWS/16, 512, 0, stream>>>(
            x, W1, b1, b2, bg, Wsk, bsk, gamma, beta,
            sb1, sb2, sbg, sbs, sgam, sbet, ws, out_proc, out_w);
    }
}